// Round 12
// baseline (664.450 us; speedup 1.0000x reference)
//
#include <hip/hip_runtime.h>

// RelationalDelayGNNStage: N=20000, E=500000, D=256, T=4, NTYPES=3
// Round 12: per-channel CSR aggregation. The R4 loop (frozen since R8) is
// latency-bound on ~25 serial branchy gather+accumulate iters/wave; every
// LOOP restructure spilled (R5/R6/R7) or regressed (R9). Fix the DATA
// STRUCTURE instead: 6 channel-CSRs (etype 0..2, hop 2..4, src-only records,
// <=2E total). Aggregation = per-(node,channel) wave, branchless 4x-unrolled
// gather-sum with ONE float4 accumulator (no branch dispatch -> no spill
// trigger), grid gains a channel axis (3-6x waves). Hop channels skipped on
// later steps. Gemm: R11's 32x128 register-dbuf LDS tile (measured ~65 us).
// Numerics: f16 operands (A scale 2^-6, W scale 2^4), fp32 accum; absmax
// pinned at fp32-reorder floor 32.0 (budget 174) since round 2.

#define NN 20000
#define NE 500000
#define DD 256
#define TT 4
#define NT 3
#define BK 32

typedef _Float16 f16;
typedef _Float16 f16x8 __attribute__((ext_vector_type(8)));
typedef _Float16 f16x4v __attribute__((ext_vector_type(4)));
typedef float f32x4 __attribute__((ext_vector_type(4)));

__device__ inline void f4add(float4& a, const float4 b) {
  a.x += b.x; a.y += b.y; a.z += b.z; a.w += b.w;
}

// ---------------- per-channel CSR build ----------------
// channel: 0..2 = etype, 3..5 = hop-2

__global__ void k_hist(const int* __restrict__ ei, const int* __restrict__ ea,
                       int* __restrict__ cnt) {
  int e = blockIdx.x * 256 + threadIdx.x;
  if (e >= NE) return;
  int dst = ei[NE + e];
  int hop = ea[2 * e];
  int et  = ea[2 * e + 1];
  atomicAdd(&cnt[et * NN + dst], 1);
  if (hop >= 2) atomicAdd(&cnt[(3 + hop - 2) * NN + dst], 1);
}

__global__ void k_scan6(const int* __restrict__ cnt, int* __restrict__ crow,
                        int* __restrict__ ccur) {
  const int TOT = 6 * NN;
  __shared__ int wsum[16];
  __shared__ int s_run;
  int tid = threadIdx.x, lane = tid & 63, wv = tid >> 6;
  if (tid == 0) s_run = 0;
  __syncthreads();
  for (int base = 0; base < TOT; base += 1024) {
    int i = base + tid;
    int v = (i < TOT) ? cnt[i] : 0;
    int s = v;
#pragma unroll
    for (int off = 1; off < 64; off <<= 1) {
      int t = __shfl_up(s, off, 64);
      if (lane >= off) s += t;
    }
    if (lane == 63) wsum[wv] = s;
    __syncthreads();
    if (wv == 0) {
      int ws = (lane < 16) ? wsum[lane] : 0;
#pragma unroll
      for (int off = 1; off < 16; off <<= 1) {
        int t = __shfl_up(ws, off, 64);
        if (lane >= off) ws += t;
      }
      if (lane < 16) wsum[lane] = ws;
    }
    __syncthreads();
    int wave_excl = (wv == 0) ? 0 : wsum[wv - 1];
    int excl = s_run + wave_excl + s - v;
    if (i < TOT) { crow[i] = excl; ccur[i] = excl; }
    __syncthreads();
    if (tid == 0) s_run += wsum[15];
    __syncthreads();
  }
  if (tid == 0) crow[TOT] = s_run;
}

__global__ void k_scatter(const int* __restrict__ ei, const int* __restrict__ ea,
                          int* __restrict__ ccur, int* __restrict__ crec) {
  int e = blockIdx.x * 256 + threadIdx.x;
  if (e >= NE) return;
  int src = ei[e];
  int dst = ei[NE + e];
  int hop = ea[2 * e];
  int et  = ea[2 * e + 1];
  int pos = atomicAdd(&ccur[et * NN + dst], 1);
  crec[pos] = src;
  if (hop >= 2) {
    int pos2 = atomicAdd(&ccur[(3 + hop - 2) * NN + dst], 1);
    crec[pos2] = src;
  }
}

// ---------------- W: fp32 -> transposed f16 (scale 2^4), LDS-tiled ----------------

__global__ __launch_bounds__(256) void k_wsplit(
    const float* __restrict__ W_edge, const float* __restrict__ W_hop,
    f16* __restrict__ Wout) {
  __shared__ float tile[64][65];
  int w = blockIdx.z;
  int tk = blockIdx.x * 64;
  int tn = blockIdx.y * 64;
  const float* src = (w < 12) ? (W_edge + (size_t)w * 65536)
                              : (W_hop + (size_t)(w - 12) * 65536);
  f16* dst = Wout + (size_t)w * 65536;
  int c = threadIdx.x & 63;
  int r0 = threadIdx.x >> 6;
#pragma unroll
  for (int i = 0; i < 16; i++) {
    int r = i * 4 + r0;
    tile[r][c] = src[(size_t)(tk + r) * 256 + tn + c] * 16.0f;
  }
  __syncthreads();
#pragma unroll
  for (int i = 0; i < 16; i++) {
    int r = i * 4 + r0;
    dst[(size_t)(tn + r) * 256 + tk + c] = (f16)tile[c][r];
  }
}

// ---------------- x fp32 -> f16 copy ----------------

__global__ void k_xcast(const float* __restrict__ x, f16* __restrict__ xh) {
  size_t i = (size_t)(blockIdx.x * 256 + threadIdx.x) * 4;
  float4 v = *(const float4*)(x + i);
  f16x4v h = { (f16)v.x, (f16)v.y, (f16)v.z, (f16)v.w };
  *(f16x4v*)(xh + i) = h;
}

// ---------------- aggregation: per-(node,channel) branchless gather-sum ----------------

__device__ inline void store_h(f16* __restrict__ p, float4 v) {
  const float s = 0.015625f;  // 2^-6
  f16x4v h = { (f16)(v.x * s), (f16)(v.y * s), (f16)(v.z * s), (f16)(v.w * s) };
  *(f16x4v*)p = h;
}

__device__ __forceinline__ float4 cvt4(f16x4v h) {
  return make_float4((float)h.x, (float)h.y, (float)h.z, (float)h.w);
}

struct AggArgs {
  f16* out[6];   // etype0..2, hop2, hop3, hop4 (null = skip channel)
};

__global__ __launch_bounds__(256) void k_aggregate(
    const f16* __restrict__ xh,
    const int* __restrict__ crow,
    const int* __restrict__ crec,
    AggArgs args)
{
  int ch = blockIdx.y;
  f16* outp = args.out[ch];
  if (!outp) return;
  int wave = threadIdx.x >> 6;
  int lane = threadIdx.x & 63;
  int v = blockIdx.x * 4 + wave;     // grid.x = NN/4, always < NN
  int base = ch * NN + v;
  int beg = crow[base], end = crow[base + 1];
  const f16* xb = xh + (lane << 2);
  float4 acc = make_float4(0, 0, 0, 0);
  int e = beg;
  for (; e + 4 <= end; e += 4) {
    int s0 = crec[e], s1 = crec[e + 1], s2 = crec[e + 2], s3 = crec[e + 3];
    f16x4v h0 = *(const f16x4v*)(xb + (size_t)s0 * DD);
    f16x4v h1 = *(const f16x4v*)(xb + (size_t)s1 * DD);
    f16x4v h2 = *(const f16x4v*)(xb + (size_t)s2 * DD);
    f16x4v h3 = *(const f16x4v*)(xb + (size_t)s3 * DD);
    float4 t0 = cvt4(h0), t1 = cvt4(h1), t2 = cvt4(h2), t3 = cvt4(h3);
    f4add(t0, t1);
    f4add(t2, t3);
    f4add(t0, t2);
    f4add(acc, t0);
  }
  for (; e < end; ++e) {
    int s0 = crec[e];
    f16x4v h0 = *(const f16x4v*)(xb + (size_t)s0 * DD);
    f4add(acc, cvt4(h0));
  }
  store_h(outp + (size_t)v * DD + (lane << 2), acc);
}

// ---------------- f16 MFMA GEMM: 32x128 tile, register-staged double buffer ----------------
// (unchanged from R11: ~65 us/dispatch measured by ledger)

struct GemmArgs {
  const f16* A[6];     // aggregates, scale 2^-6
  const f16* W[6];     // transposed, scale 2^4
  const float* bias[6];
  const int*   cnt[6];
  int nch;
  int write_f32;       // 1 on final step
  const f16* xh_in;
  f16*       xh_out;
  float*     f32_out;
};

__global__ __launch_bounds__(256) void k_gemm(GemmArgs args) {
  __shared__ __align__(16) f16 sA[2][32 * BK];     // 2 x 2 KB
  __shared__ __align__(16) f16 sB[2][128 * BK];    // 2 x 8 KB
  const int tid = threadIdx.x;
  const int lane = tid & 63;
  const int wave = tid >> 6;
  const int wm = (wave >> 1) * 16;    // 0 or 16
  const int wn = (wave & 1) * 64;     // 0 or 64 (within 128-col tile)
  const int m0 = blockIdx.x * 32;     // 625*32 = 20000 exact
  const int n0 = blockIdx.y * 128;    // 2 halves
  const int nch = args.nch;
  const int T = nch * 8;

  f32x4 acc[4];
#pragma unroll
  for (int j = 0; j < 4; j++) acc[j] = (f32x4){0.f, 0.f, 0.f, 0.f};

  const bool doA = (tid < 128);
  const int ar = (tid & 127) >> 2, aq = tid & 3;
  const int ag = ar * 512 + aq * 16;
  const int al = ar * 64 + ((aq ^ ((ar >> 1) & 3)) << 4);
  int bg[2], bl[2];
#pragma unroll
  for (int i = 0; i < 2; i++) {
    int s = i * 256 + tid;
    int r = s >> 2, q = s & 3;
    bg[i] = r * 512 + q * 16;
    bl[i] = r * 64 + ((q ^ ((r >> 1) & 3)) << 4);
  }

  const int fr = lane & 15;
  const int gq = lane >> 4;
  int offA, offB[4];
  {
    int rr = wm + fr;
    offA = rr * BK + ((gq ^ ((rr >> 1) & 3)) << 3);
  }
#pragma unroll
  for (int ni = 0; ni < 4; ni++) {
    int rr = wn + ni * 16 + fr;
    offB[ni] = rr * BK + ((gq ^ ((rr >> 1) & 3)) << 3);
  }

  f16x8 rA, rB[2];
  {
    const char* pa = (const char*)args.A[0] + (size_t)m0 * 512;
    const char* pb = (const char*)args.W[0] + (size_t)n0 * 512;
    if (doA) rA = *(const f16x8*)(pa + ag);
#pragma unroll
    for (int i = 0; i < 2; i++) rB[i] = *(const f16x8*)(pb + bg[i]);
  }
  if (doA) *(f16x8*)((char*)sA[0] + al) = rA;
#pragma unroll
  for (int i = 0; i < 2; i++) *(f16x8*)((char*)sB[0] + bl[i]) = rB[i];
  __syncthreads();

  for (int j = 0; j < T; ++j) {
    const int p = j & 1;
    {
      int jn = (j + 1 < T) ? j + 1 : j;
      int c = jn >> 3, kb = (jn & 7) * 64;
      const char* pa = (const char*)args.A[c] + (size_t)m0 * 512 + kb;
      const char* pb = (const char*)args.W[c] + (size_t)n0 * 512 + kb;
      if (doA) rA = *(const f16x8*)(pa + ag);
#pragma unroll
      for (int i = 0; i < 2; i++) rB[i] = *(const f16x8*)(pb + bg[i]);
    }
    {
      f16x8 fA, fB[4];
      fA = *(const f16x8*)&sA[p][offA];
#pragma unroll
      for (int ni = 0; ni < 4; ni++) fB[ni] = *(const f16x8*)&sB[p][offB[ni]];
#pragma unroll
      for (int ni = 0; ni < 4; ni++)
        acc[ni] = __builtin_amdgcn_mfma_f32_16x16x32_f16(fA, fB[ni], acc[ni], 0, 0, 0);
    }
    if (doA) *(f16x8*)((char*)sA[p ^ 1] + al) = rA;
#pragma unroll
    for (int i = 0; i < 2; i++) *(f16x8*)((char*)sB[p ^ 1] + bl[i]) = rB[i];
    __syncthreads();
  }

  // epilogue: out = xh + relu(acc*4 + sum_c cnt_c[row]*b_c[col]);  4 = 2^6*2^-4
  float bcol[4][6];
#pragma unroll
  for (int ni = 0; ni < 4; ni++) {
    int gcol = n0 + wn + ni * 16 + fr;
#pragma unroll
    for (int c = 0; c < 6; c++)
      bcol[ni][c] = (c < nch) ? args.bias[c][gcol] : 0.f;
  }
  const int rowq = gq * 4;
#pragma unroll
  for (int rI = 0; rI < 4; rI++) {
    int grow = m0 + wm + rowq + rI;
    float cv[6];
#pragma unroll
    for (int c = 0; c < 6; c++)
      cv[c] = (c < nch) ? (float)args.cnt[c][grow] : 0.f;
    size_t rowoff = (size_t)grow * DD;
#pragma unroll
    for (int ni = 0; ni < 4; ni++) {
      int gcol = n0 + wn + ni * 16 + fr;
      float v = acc[ni][rI] * 4.0f;
#pragma unroll
      for (int c = 0; c < 6; c++) v += cv[c] * bcol[ni][c];
      float outv = (float)args.xh_in[rowoff + gcol] + fmaxf(v, 0.f);
      args.xh_out[rowoff + gcol] = (f16)outv;
      if (args.write_f32) args.f32_out[rowoff + gcol] = outv;
    }
  }
}

// ---------------- host ----------------

extern "C" void kernel_launch(void* const* d_in, const int* in_sizes, int n_in,
                              void* d_out, int out_size, void* d_ws, size_t ws_size,
                              hipStream_t stream) {
  const float* x      = (const float*)d_in[0];
  const int* edge_index = (const int*)d_in[1];
  const int* edge_attr  = (const int*)d_in[2];
  const float* W_edge = (const float*)d_in[3];
  const float* b_edge = (const float*)d_in[4];
  const float* W_hop  = (const float*)d_in[5];
  const float* b_hop  = (const float*)d_in[6];
  float* out = (float*)d_out;

  // workspace layout
  char* ws = (char*)d_ws;
  int* cnt  = (int*)ws;               // 6N   (also GEMM bias counts)
  int* crow = cnt + 6 * NN;           // 6N+1
  int* ccur = crow + 6 * NN + 1;      // 6N
  int* crec = ccur + 6 * NN;          // up to 2E
  size_t int_count = (size_t)6 * NN + (6 * NN + 1) + 6 * NN + 2 * (size_t)NE;
  const size_t ND = (size_t)NN * DD;
  f16* Wsplit = (f16*)(ws + ((int_count * 4 + 255) & ~(size_t)255));  // 24 * 65536 f16
  f16* xh = Wsplit + (size_t)24 * 65536;                              // N*D f16
  f16* aggBase = xh + ND;
  f16* agg[9];
  for (int i = 0; i < 9; i++) agg[i] = aggBase + (size_t)i * ND;
  f16** Cb = agg + 3;  // Cb[0..5]: C2_s0,C2_s1,C2_s2, C3_s0,C3_s1, C4_s0

  hipMemsetAsync(cnt, 0, 6 * NN * sizeof(int), stream);

  k_hist<<<(NE + 255) / 256, 256, 0, stream>>>(edge_index, edge_attr, cnt);
  k_scan6<<<1, 1024, 0, stream>>>(cnt, crow, ccur);
  k_scatter<<<(NE + 255) / 256, 256, 0, stream>>>(edge_index, edge_attr, ccur, crec);
  k_wsplit<<<dim3(4, 4, 24), 256, 0, stream>>>(W_edge, W_hop, Wsplit);
  k_xcast<<<ND / 1024, 256, 0, stream>>>(x, xh);

  for (int t = 0; t < TT; ++t) {
    AggArgs aa{};
    aa.out[0] = agg[0];
    aa.out[1] = agg[1];
    aa.out[2] = agg[2];
    aa.out[3] = (t <= 2) ? Cb[t]     : nullptr;   // hop2 of step t
    aa.out[4] = (t <= 1) ? Cb[3 + t] : nullptr;   // hop3 of step t
    aa.out[5] = (t == 0) ? Cb[5]     : nullptr;   // hop4 of step t
    k_aggregate<<<dim3(NN / 4, 6), 256, 0, stream>>>(xh, crow, crec, aa);

    GemmArgs ga{};
    for (int e = 0; e < NT; ++e) {
      ga.A[e]    = agg[e];
      ga.W[e]    = Wsplit + (size_t)(t * NT + e) * 65536;
      ga.bias[e] = b_edge + (size_t)(t * NT + e) * DD;
      ga.cnt[e]  = cnt + (size_t)e * NN;
    }
    int nc = NT;
    for (int k = 2; k <= t + 1; ++k) {
      int s = t + 1 - k;
      ga.A[nc]    = (k == 2) ? Cb[s] : (k == 3) ? Cb[3 + s] : Cb[5];
      ga.W[nc]    = Wsplit + (size_t)(12 + t * 3 + (k - 2)) * 65536;
      ga.bias[nc] = b_hop + (size_t)(t * (TT - 1) + (k - 2)) * DD;
      ga.cnt[nc]  = cnt + (size_t)(3 + (k - 2)) * NN;
      nc++;
    }
    for (int c = nc; c < 6; ++c) {
      ga.A[c] = ga.A[0]; ga.W[c] = ga.W[0]; ga.bias[c] = ga.bias[0]; ga.cnt[c] = ga.cnt[0];
    }
    ga.nch = nc;
    ga.write_f32 = (t == TT - 1) ? 1 : 0;
    ga.xh_in  = xh;
    ga.xh_out = xh;
    ga.f32_out = out;
    k_gemm<<<dim3(625, 2), 256, 0, stream>>>(ga);
  }
}

// Round 13
// 554.869 us; speedup vs baseline: 1.1975x; 1.1975x over previous
//
#include <hip/hip_runtime.h>

// RelationalDelayGNNStage: N=20000, E=500000, D=256, T=4, NTYPES=3
// Round 13: fix R12's self-inflicted serial bottleneck — the single-block
// scan over 6N=120001 elements ran 116 us on ONE CU (top kernel). Replaced
// with a hierarchical 3-kernel scan (block-scan 118x1024 -> top-scan 118 ->
// fixup): ~10 us total. Aggregate (per-channel CSR, branchless 4x gather-sum)
// and gemm (32x128 register-dbuf LDS) unchanged from R12.
// Numerics: f16 operands (A scale 2^-6, W scale 2^4), fp32 accum; absmax
// pinned at fp32-reorder floor 32.0 (budget 174) since round 2.

#define NN 20000
#define NE 500000
#define DD 256
#define TT 4
#define NT 3
#define BK 32
#define NB 118   // ceil(6*NN / 1024)

typedef _Float16 f16;
typedef _Float16 f16x8 __attribute__((ext_vector_type(8)));
typedef _Float16 f16x4v __attribute__((ext_vector_type(4)));
typedef float f32x4 __attribute__((ext_vector_type(4)));

__device__ inline void f4add(float4& a, const float4 b) {
  a.x += b.x; a.y += b.y; a.z += b.z; a.w += b.w;
}

// ---------------- per-channel CSR build ----------------
// channel: 0..2 = etype, 3..5 = hop-2

__global__ void k_hist(const int* __restrict__ ei, const int* __restrict__ ea,
                       int* __restrict__ cnt) {
  int e = blockIdx.x * 256 + threadIdx.x;
  if (e >= NE) return;
  int dst = ei[NE + e];
  int hop = ea[2 * e];
  int et  = ea[2 * e + 1];
  atomicAdd(&cnt[et * NN + dst], 1);
  if (hop >= 2) atomicAdd(&cnt[(3 + hop - 2) * NN + dst], 1);
}

// hierarchical scan over cnt[6N] -> crow (exclusive), ccur copy, crow[6N]=total

__global__ __launch_bounds__(1024) void k_scan_blk(
    const int* __restrict__ cnt, int* __restrict__ crow, int* __restrict__ bsum) {
  __shared__ int wsum[16];
  int tid = threadIdx.x, lane = tid & 63, wv = tid >> 6;
  int i = blockIdx.x * 1024 + tid;
  int v = (i < 6 * NN) ? cnt[i] : 0;
  int s = v;
#pragma unroll
  for (int off = 1; off < 64; off <<= 1) {
    int t = __shfl_up(s, off, 64);
    if (lane >= off) s += t;
  }
  if (lane == 63) wsum[wv] = s;
  __syncthreads();
  if (wv == 0) {
    int ws = (lane < 16) ? wsum[lane] : 0;
#pragma unroll
    for (int off = 1; off < 16; off <<= 1) {
      int t = __shfl_up(ws, off, 64);
      if (lane >= off) ws += t;
    }
    if (lane < 16) wsum[lane] = ws;
  }
  __syncthreads();
  int excl = ((wv == 0) ? 0 : wsum[wv - 1]) + s - v;
  if (i < 6 * NN) crow[i] = excl;
  if (tid == 1023) bsum[blockIdx.x] = wsum[15];
}

__global__ __launch_bounds__(128) void k_scan_top(
    int* __restrict__ bsum, int* __restrict__ crow) {
  __shared__ int wsum2[2];
  int tid = threadIdx.x, lane = tid & 63, wv = tid >> 6;
  int v = (tid < NB) ? bsum[tid] : 0;
  int s = v;
#pragma unroll
  for (int off = 1; off < 64; off <<= 1) {
    int t = __shfl_up(s, off, 64);
    if (lane >= off) s += t;
  }
  if (lane == 63) wsum2[wv] = s;
  __syncthreads();
  int add = (wv == 1) ? wsum2[0] : 0;
  int excl = add + s - v;
  if (tid < NB) bsum[tid] = excl;
  if (tid == NB - 1) crow[6 * NN] = excl + v;
}

__global__ __launch_bounds__(1024) void k_scan_fix(
    int* __restrict__ crow, int* __restrict__ ccur, const int* __restrict__ bsum) {
  int i = blockIdx.x * 1024 + threadIdx.x;
  if (i >= 6 * NN) return;
  int val = crow[i] + bsum[blockIdx.x];
  crow[i] = val;
  ccur[i] = val;
}

__global__ void k_scatter(const int* __restrict__ ei, const int* __restrict__ ea,
                          int* __restrict__ ccur, int* __restrict__ crec) {
  int e = blockIdx.x * 256 + threadIdx.x;
  if (e >= NE) return;
  int src = ei[e];
  int dst = ei[NE + e];
  int hop = ea[2 * e];
  int et  = ea[2 * e + 1];
  int pos = atomicAdd(&ccur[et * NN + dst], 1);
  crec[pos] = src;
  if (hop >= 2) {
    int pos2 = atomicAdd(&ccur[(3 + hop - 2) * NN + dst], 1);
    crec[pos2] = src;
  }
}

// ---------------- W: fp32 -> transposed f16 (scale 2^4), LDS-tiled ----------------

__global__ __launch_bounds__(256) void k_wsplit(
    const float* __restrict__ W_edge, const float* __restrict__ W_hop,
    f16* __restrict__ Wout) {
  __shared__ float tile[64][65];
  int w = blockIdx.z;
  int tk = blockIdx.x * 64;
  int tn = blockIdx.y * 64;
  const float* src = (w < 12) ? (W_edge + (size_t)w * 65536)
                              : (W_hop + (size_t)(w - 12) * 65536);
  f16* dst = Wout + (size_t)w * 65536;
  int c = threadIdx.x & 63;
  int r0 = threadIdx.x >> 6;
#pragma unroll
  for (int i = 0; i < 16; i++) {
    int r = i * 4 + r0;
    tile[r][c] = src[(size_t)(tk + r) * 256 + tn + c] * 16.0f;
  }
  __syncthreads();
#pragma unroll
  for (int i = 0; i < 16; i++) {
    int r = i * 4 + r0;
    dst[(size_t)(tn + r) * 256 + tk + c] = (f16)tile[c][r];
  }
}

// ---------------- x fp32 -> f16 copy ----------------

__global__ void k_xcast(const float* __restrict__ x, f16* __restrict__ xh) {
  size_t i = (size_t)(blockIdx.x * 256 + threadIdx.x) * 4;
  float4 v = *(const float4*)(x + i);
  f16x4v h = { (f16)v.x, (f16)v.y, (f16)v.z, (f16)v.w };
  *(f16x4v*)(xh + i) = h;
}

// ---------------- aggregation: per-(node,channel) branchless gather-sum ----------------

__device__ inline void store_h(f16* __restrict__ p, float4 v) {
  const float s = 0.015625f;  // 2^-6
  f16x4v h = { (f16)(v.x * s), (f16)(v.y * s), (f16)(v.z * s), (f16)(v.w * s) };
  *(f16x4v*)p = h;
}

__device__ __forceinline__ float4 cvt4(f16x4v h) {
  return make_float4((float)h.x, (float)h.y, (float)h.z, (float)h.w);
}

struct AggArgs {
  f16* out[6];   // etype0..2, hop2, hop3, hop4 (null = skip channel)
};

__global__ __launch_bounds__(256) void k_aggregate(
    const f16* __restrict__ xh,
    const int* __restrict__ crow,
    const int* __restrict__ crec,
    AggArgs args)
{
  int ch = blockIdx.y;
  f16* outp = args.out[ch];
  if (!outp) return;
  int wave = threadIdx.x >> 6;
  int lane = threadIdx.x & 63;
  int v = blockIdx.x * 4 + wave;     // grid.x = NN/4, always < NN
  int base = ch * NN + v;
  int beg = crow[base], end = crow[base + 1];
  const f16* xb = xh + (lane << 2);
  float4 acc = make_float4(0, 0, 0, 0);
  int e = beg;
  for (; e + 4 <= end; e += 4) {
    int s0 = crec[e], s1 = crec[e + 1], s2 = crec[e + 2], s3 = crec[e + 3];
    f16x4v h0 = *(const f16x4v*)(xb + (size_t)s0 * DD);
    f16x4v h1 = *(const f16x4v*)(xb + (size_t)s1 * DD);
    f16x4v h2 = *(const f16x4v*)(xb + (size_t)s2 * DD);
    f16x4v h3 = *(const f16x4v*)(xb + (size_t)s3 * DD);
    float4 t0 = cvt4(h0), t1 = cvt4(h1), t2 = cvt4(h2), t3 = cvt4(h3);
    f4add(t0, t1);
    f4add(t2, t3);
    f4add(t0, t2);
    f4add(acc, t0);
  }
  for (; e < end; ++e) {
    int s0 = crec[e];
    f16x4v h0 = *(const f16x4v*)(xb + (size_t)s0 * DD);
    f4add(acc, cvt4(h0));
  }
  store_h(outp + (size_t)v * DD + (lane << 2), acc);
}

// ---------------- f16 MFMA GEMM: 32x128 tile, register-staged double buffer ----------------

struct GemmArgs {
  const f16* A[6];     // aggregates, scale 2^-6
  const f16* W[6];     // transposed, scale 2^4
  const float* bias[6];
  const int*   cnt[6];
  int nch;
  int write_f32;       // 1 on final step
  const f16* xh_in;
  f16*       xh_out;
  float*     f32_out;
};

__global__ __launch_bounds__(256) void k_gemm(GemmArgs args) {
  __shared__ __align__(16) f16 sA[2][32 * BK];     // 2 x 2 KB
  __shared__ __align__(16) f16 sB[2][128 * BK];    // 2 x 8 KB
  const int tid = threadIdx.x;
  const int lane = tid & 63;
  const int wave = tid >> 6;
  const int wm = (wave >> 1) * 16;    // 0 or 16
  const int wn = (wave & 1) * 64;     // 0 or 64 (within 128-col tile)
  const int m0 = blockIdx.x * 32;     // 625*32 = 20000 exact
  const int n0 = blockIdx.y * 128;    // 2 halves
  const int nch = args.nch;
  const int T = nch * 8;

  f32x4 acc[4];
#pragma unroll
  for (int j = 0; j < 4; j++) acc[j] = (f32x4){0.f, 0.f, 0.f, 0.f};

  const bool doA = (tid < 128);
  const int ar = (tid & 127) >> 2, aq = tid & 3;
  const int ag = ar * 512 + aq * 16;
  const int al = ar * 64 + ((aq ^ ((ar >> 1) & 3)) << 4);
  int bg[2], bl[2];
#pragma unroll
  for (int i = 0; i < 2; i++) {
    int s = i * 256 + tid;
    int r = s >> 2, q = s & 3;
    bg[i] = r * 512 + q * 16;
    bl[i] = r * 64 + ((q ^ ((r >> 1) & 3)) << 4);
  }

  const int fr = lane & 15;
  const int gq = lane >> 4;
  int offA, offB[4];
  {
    int rr = wm + fr;
    offA = rr * BK + ((gq ^ ((rr >> 1) & 3)) << 3);
  }
#pragma unroll
  for (int ni = 0; ni < 4; ni++) {
    int rr = wn + ni * 16 + fr;
    offB[ni] = rr * BK + ((gq ^ ((rr >> 1) & 3)) << 3);
  }

  f16x8 rA, rB[2];
  {
    const char* pa = (const char*)args.A[0] + (size_t)m0 * 512;
    const char* pb = (const char*)args.W[0] + (size_t)n0 * 512;
    if (doA) rA = *(const f16x8*)(pa + ag);
#pragma unroll
    for (int i = 0; i < 2; i++) rB[i] = *(const f16x8*)(pb + bg[i]);
  }
  if (doA) *(f16x8*)((char*)sA[0] + al) = rA;
#pragma unroll
  for (int i = 0; i < 2; i++) *(f16x8*)((char*)sB[0] + bl[i]) = rB[i];
  __syncthreads();

  for (int j = 0; j < T; ++j) {
    const int p = j & 1;
    {
      int jn = (j + 1 < T) ? j + 1 : j;
      int c = jn >> 3, kb = (jn & 7) * 64;
      const char* pa = (const char*)args.A[c] + (size_t)m0 * 512 + kb;
      const char* pb = (const char*)args.W[c] + (size_t)n0 * 512 + kb;
      if (doA) rA = *(const f16x8*)(pa + ag);
#pragma unroll
      for (int i = 0; i < 2; i++) rB[i] = *(const f16x8*)(pb + bg[i]);
    }
    {
      f16x8 fA, fB[4];
      fA = *(const f16x8*)&sA[p][offA];
#pragma unroll
      for (int ni = 0; ni < 4; ni++) fB[ni] = *(const f16x8*)&sB[p][offB[ni]];
#pragma unroll
      for (int ni = 0; ni < 4; ni++)
        acc[ni] = __builtin_amdgcn_mfma_f32_16x16x32_f16(fA, fB[ni], acc[ni], 0, 0, 0);
    }
    if (doA) *(f16x8*)((char*)sA[p ^ 1] + al) = rA;
#pragma unroll
    for (int i = 0; i < 2; i++) *(f16x8*)((char*)sB[p ^ 1] + bl[i]) = rB[i];
    __syncthreads();
  }

  // epilogue: out = xh + relu(acc*4 + sum_c cnt_c[row]*b_c[col]);  4 = 2^6*2^-4
  float bcol[4][6];
#pragma unroll
  for (int ni = 0; ni < 4; ni++) {
    int gcol = n0 + wn + ni * 16 + fr;
#pragma unroll
    for (int c = 0; c < 6; c++)
      bcol[ni][c] = (c < nch) ? args.bias[c][gcol] : 0.f;
  }
  const int rowq = gq * 4;
#pragma unroll
  for (int rI = 0; rI < 4; rI++) {
    int grow = m0 + wm + rowq + rI;
    float cv[6];
#pragma unroll
    for (int c = 0; c < 6; c++)
      cv[c] = (c < nch) ? (float)args.cnt[c][grow] : 0.f;
    size_t rowoff = (size_t)grow * DD;
#pragma unroll
    for (int ni = 0; ni < 4; ni++) {
      int gcol = n0 + wn + ni * 16 + fr;
      float v = acc[ni][rI] * 4.0f;
#pragma unroll
      for (int c = 0; c < 6; c++) v += cv[c] * bcol[ni][c];
      float outv = (float)args.xh_in[rowoff + gcol] + fmaxf(v, 0.f);
      args.xh_out[rowoff + gcol] = (f16)outv;
      if (args.write_f32) args.f32_out[rowoff + gcol] = outv;
    }
  }
}

// ---------------- host ----------------

extern "C" void kernel_launch(void* const* d_in, const int* in_sizes, int n_in,
                              void* d_out, int out_size, void* d_ws, size_t ws_size,
                              hipStream_t stream) {
  const float* x      = (const float*)d_in[0];
  const int* edge_index = (const int*)d_in[1];
  const int* edge_attr  = (const int*)d_in[2];
  const float* W_edge = (const float*)d_in[3];
  const float* b_edge = (const float*)d_in[4];
  const float* W_hop  = (const float*)d_in[5];
  const float* b_hop  = (const float*)d_in[6];
  float* out = (float*)d_out;

  // workspace layout
  char* ws = (char*)d_ws;
  int* cnt  = (int*)ws;               // 6N   (also GEMM bias counts)
  int* crow = cnt + 6 * NN;           // 6N+1
  int* ccur = crow + 6 * NN + 1;      // 6N
  int* bsum = ccur + 6 * NN;          // NB
  int* crec = bsum + NB;              // up to 2E
  size_t int_count = (size_t)6 * NN + (6 * NN + 1) + 6 * NN + NB + 2 * (size_t)NE;
  const size_t ND = (size_t)NN * DD;
  f16* Wsplit = (f16*)(ws + ((int_count * 4 + 255) & ~(size_t)255));  // 24 * 65536 f16
  f16* xh = Wsplit + (size_t)24 * 65536;                              // N*D f16
  f16* aggBase = xh + ND;
  f16* agg[9];
  for (int i = 0; i < 9; i++) agg[i] = aggBase + (size_t)i * ND;
  f16** Cb = agg + 3;  // Cb[0..5]: C2_s0,C2_s1,C2_s2, C3_s0,C3_s1, C4_s0

  hipMemsetAsync(cnt, 0, 6 * NN * sizeof(int), stream);

  k_hist<<<(NE + 255) / 256, 256, 0, stream>>>(edge_index, edge_attr, cnt);
  k_scan_blk<<<NB, 1024, 0, stream>>>(cnt, crow, bsum);
  k_scan_top<<<1, 128, 0, stream>>>(bsum, crow);
  k_scan_fix<<<NB, 1024, 0, stream>>>(crow, ccur, bsum);
  k_scatter<<<(NE + 255) / 256, 256, 0, stream>>>(edge_index, edge_attr, ccur, crec);
  k_wsplit<<<dim3(4, 4, 24), 256, 0, stream>>>(W_edge, W_hop, Wsplit);
  k_xcast<<<ND / 1024, 256, 0, stream>>>(x, xh);

  for (int t = 0; t < TT; ++t) {
    AggArgs aa{};
    aa.out[0] = agg[0];
    aa.out[1] = agg[1];
    aa.out[2] = agg[2];
    aa.out[3] = (t <= 2) ? Cb[t]     : nullptr;   // hop2 of step t
    aa.out[4] = (t <= 1) ? Cb[3 + t] : nullptr;   // hop3 of step t
    aa.out[5] = (t == 0) ? Cb[5]     : nullptr;   // hop4 of step t
    k_aggregate<<<dim3(NN / 4, 6), 256, 0, stream>>>(xh, crow, crec, aa);

    GemmArgs ga{};
    for (int e = 0; e < NT; ++e) {
      ga.A[e]    = agg[e];
      ga.W[e]    = Wsplit + (size_t)(t * NT + e) * 65536;
      ga.bias[e] = b_edge + (size_t)(t * NT + e) * DD;
      ga.cnt[e]  = cnt + (size_t)e * NN;
    }
    int nc = NT;
    for (int k = 2; k <= t + 1; ++k) {
      int s = t + 1 - k;
      ga.A[nc]    = (k == 2) ? Cb[s] : (k == 3) ? Cb[3 + s] : Cb[5];
      ga.W[nc]    = Wsplit + (size_t)(12 + t * 3 + (k - 2)) * 65536;
      ga.bias[nc] = b_hop + (size_t)(t * (TT - 1) + (k - 2)) * DD;
      ga.cnt[nc]  = cnt + (size_t)(3 + (k - 2)) * NN;
      nc++;
    }
    for (int c = nc; c < 6; ++c) {
      ga.A[c] = ga.A[0]; ga.W[c] = ga.W[0]; ga.bias[c] = ga.bias[0]; ga.cnt[c] = ga.cnt[0];
    }
    ga.nch = nc;
    ga.write_f32 = (t == TT - 1) ? 1 : 0;
    ga.xh_in  = xh;
    ga.xh_out = xh;
    ga.f32_out = out;
    k_gemm<<<dim3(625, 2), 256, 0, stream>>>(ga);
  }
}